// Round 3
// baseline (866.491 us; speedup 1.0000x reference)
//
#include <hip/hip_runtime.h>
#include <hip/hip_bf16.h>

typedef __attribute__((ext_vector_type(8))) short bf16x8;
typedef __attribute__((ext_vector_type(4))) float f32x4;
typedef __attribute__((ext_vector_type(8))) unsigned short ushort8;

__device__ __forceinline__ float bf2f(unsigned int u) {
  union { unsigned int i; float f; } v; v.i = u << 16; return v.f;
}
__device__ __forceinline__ unsigned short f2bf(float f) {
  __hip_bfloat16 h = __float2bfloat16(f);
  unsigned short u; __builtin_memcpy(&u, &h, 2); return u;
}
__device__ __forceinline__ unsigned int pk2(float a, float b) {
  return (unsigned int)f2bf(a) | ((unsigned int)f2bf(b) << 16);
}

// ---------------------------------------------------------------------------
// Kernel P: convert qkv_w (384x128) and proj_w (128x128) fp32 -> bf16 in ws
// ---------------------------------------------------------------------------
__global__ void k_prep(const float* __restrict__ qkvw, const float* __restrict__ projw,
                       unsigned short* __restrict__ qkvw_bf,
                       unsigned short* __restrict__ projw_bf) {
  int t = blockIdx.x * 256 + threadIdx.x;   // 16384 threads x 4 elements
  int i = t * 4;
  const float* src;
  unsigned short* dst;
  int idx;
  if (i < 49152) { src = qkvw; dst = qkvw_bf; idx = i; }
  else           { src = projw; dst = projw_bf; idx = i - 49152; }
  float4 v = *(const float4*)(src + idx);
  uint2 o; o.x = pk2(v.x, v.y); o.y = pk2(v.z, v.w);
  *(uint2*)(dst + idx) = o;
}

// ---------------------------------------------------------------------------
// Kernel B: b2dp[h][query][key64] fp32, key-padded to 64 (pad = 0)
// ---------------------------------------------------------------------------
__global__ void k_biasp(const float* __restrict__ bt, const int* __restrict__ ri,
                        float* __restrict__ b2dp) {
  int t = blockIdx.x * 256 + threadIdx.x;   // 12544 exact
  int h = t / 3136;
  int r = t - h * 3136;
  int q = r >> 6, k = r & 63;
  b2dp[t] = (k < 49) ? bt[ri[q * 49 + k] * 4 + h] : 0.f;
}

// ---------------------------------------------------------------------------
// Kernel M: maskp[wrem][query][key64] bf16, pad keys baked to -100
// ---------------------------------------------------------------------------
__global__ void k_maskp(const float* __restrict__ am, unsigned short* __restrict__ maskp) {
  int t = blockIdx.x * 256 + threadIdx.x;   // 802816 exact
  int w = t / 3136;
  int r = t - w * 3136;
  int q = r >> 6, k = r & 63;
  maskp[t] = f2bf((k < 49) ? am[w * 2401 + q * 49 + k] : -100.f);
}

// ---------------------------------------------------------------------------
// Kernel 1: LayerNorm over C + cyclic shift (-3,-3) + window partition.
// Single pass: channels retained bf16-packed in 64 VGPRs (no 2nd global read).
// ---------------------------------------------------------------------------
__global__ __launch_bounds__(256, 4) void k_ln(const float* __restrict__ x,
                                               const float* __restrict__ nw,
                                               const float* __restrict__ nb,
                                               unsigned short* __restrict__ xw) {
  int p = blockIdx.x * 256 + threadIdx.x;   // 0 .. 401407 (exact)
  int b = p / 12544;
  int r = p - b * 12544;
  int hh = r / 112;
  int wp = r - hh * 112;
  const float* bx = x + (size_t)b * 1605632 + r;

  unsigned int xb[64];
  float sum = 0.f, ss = 0.f;
  #pragma unroll
  for (int cg = 0; cg < 64; ++cg) {
    float v0 = bx[(size_t)(2 * cg) * 12544];
    float v1 = bx[(size_t)(2 * cg + 1) * 12544];
    sum += v0 + v1; ss += v0 * v0 + v1 * v1;
    xb[cg] = pk2(v0, v1);
  }
  float mu = sum * 0.0078125f;
  float var = ss * 0.0078125f - mu * mu;
  float rstd = rsqrtf(var + 1e-5f);

  int h2 = hh + 109; if (h2 >= 112) h2 -= 112;
  int w2 = wp + 109; if (w2 >= 112) w2 -= 112;
  int wh = h2 / 7, ii = h2 - wh * 7;
  int ww = w2 / 7, jj = w2 - ww * 7;
  int winl = (b * 16 + wh) * 16 + ww;
  unsigned short* dst = xw + ((size_t)winl * 49 + ii * 7 + jj) * 128;

  #pragma unroll
  for (int g = 0; g < 4; ++g) {
    unsigned int pkk[16];
    #pragma unroll
    for (int q = 0; q < 16; ++q) {
      int cg = g * 16 + q;
      unsigned int u = xb[cg];
      float v0 = bf2f(u & 0xffffu), v1 = bf2f(u >> 16);
      int c = 2 * cg;
      float y0 = (v0 - mu) * rstd * nw[c] + nb[c];
      float y1 = (v1 - mu) * rstd * nw[c + 1] + nb[c + 1];
      pkk[q] = pk2(y0, y1);
    }
    uint4* d4 = (uint4*)(dst + g * 32);
    #pragma unroll
    for (int k = 0; k < 4; ++k)
      d4[k] = make_uint4(pkk[4 * k], pkk[4 * k + 1], pkk[4 * k + 2], pkk[4 * k + 3]);
  }
}

// ---------------------------------------------------------------------------
// Kernel 2: fused window attention. 1 block = 1 window, 512 thr = 8 waves.
// wave wid: h = wid&3 (head), half = wid>>2 (token/key half).
// Orientations chosen so all LDS stores are b64 and all frag loads b128:
//   Q,K: D' = Wqk . X^T  (lane: [token=m15][dims quad*4+rr] -> b64 row-major)
//   V:   D  = X . Wv^T   -> V^T[dim][key]  (keys quad*4+rr -> b64)
//   S^T  = K . Q^T       (lane: [key=quad*4+rr][query=m15]); softmax w/o max-sub
//   O^T  = V^T . P       (lane: [query=m15][dims quad*4+rr] -> b64)
//   Y^T  = Wp . O^T      (lane: [token=m15][couts quad*4+rr] -> 8B global store)
// LDS/head (14848): Q[64x80] K[64x80] V^T[32x144]; P/O[64x144] overlay Q+K.
// X stage [64x272] overlays heads 0/1 (dead after xf). partials @59392 (2KB).
// ---------------------------------------------------------------------------
__global__ __launch_bounds__(512, 4) void k_attn(
    const unsigned short* __restrict__ xw,
    const unsigned short* __restrict__ qkvw,
    const float* __restrict__ qkvb,
    const unsigned short* __restrict__ projw,
    const float* __restrict__ projb,
    const float* __restrict__ b2dp,
    const unsigned short* __restrict__ maskp,
    unsigned short* __restrict__ yw) {
  __shared__ __attribute__((aligned(16))) char smem[61440];
  float* part = (float*)(smem + 59392);
  const int tid  = threadIdx.x;
  const int lane = tid & 63;
  const int wid  = tid >> 6;
  const int h    = wid & 3;
  const int half = wid >> 2;
  const int m15  = lane & 15;
  const int quad = lane >> 4;
  const int win  = blockIdx.x;
  const int b    = win >> 8;
  const int wrem = win & 255;
  const int wh   = wrem >> 4;
  const int ww   = wrem & 15;
  const f32x4 fz = {0.f, 0.f, 0.f, 0.f};

  // ---- stage X window (49x128 bf16, zero-pad to 64 rows), stride 272 ----
  {
    const uint4* gsrc = (const uint4*)(xw + (size_t)win * 6272);
    #pragma unroll
    for (int it = 0; it < 2; ++it) {
      int cc = tid + it * 512;                 // 16B chunk 0..1023
      int row = cc >> 4, col = cc & 15;
      uint4 v = make_uint4(0u, 0u, 0u, 0u);
      if (cc < 784) v = gsrc[cc];
      *(uint4*)(smem + row * 272 + col * 16) = v;
    }
  }
  __syncthreads();                                             // S1
  bf16x8 xf[2][4];                 // wave's 2 token-tiles, A/B-frag layout
  #pragma unroll
  for (int t = 0; t < 2; ++t)
    #pragma unroll
    for (int kt = 0; kt < 4; ++kt)
      xf[t][kt] = *(const bf16x8*)(smem + ((half * 2 + t) * 16 + m15) * 272 + kt * 64 + quad * 16);
  __syncthreads();                                             // S2 (X dead)

  char* const Hq = smem + h * 14848;
  char* const Hk = Hq + 5120;
  char* const Hv = Hq + 10240;

  // ---- Q, K: swapped orientation (A = W rows, B = X rows) ----
  #pragma unroll
  for (int g = 0; g < 2; ++g) {
    char* dst = g ? Hk : Hq;
    #pragma unroll
    for (int ft = 0; ft < 2; ++ft) {
      int grow = g * 128 + h * 32 + ft * 16 + m15;
      bf16x8 wf[4];
      #pragma unroll
      for (int kt = 0; kt < 4; ++kt)
        wf[kt] = *(const bf16x8*)(qkvw + grow * 128 + kt * 32 + quad * 8);
      float4 b4 = *(const float4*)(qkvb + g * 128 + h * 32 + ft * 16 + 4 * quad);
      #pragma unroll
      for (int t = 0; t < 2; ++t) {
        f32x4 acc = fz;
        #pragma unroll
        for (int kt = 0; kt < 4; ++kt)
          acc = __builtin_amdgcn_mfma_f32_16x16x32_bf16(wf[kt], xf[t][kt], acc, 0, 0, 0);
        int token = (half * 2 + t) * 16 + m15;
        uint2 u;
        u.x = pk2(acc[0] + b4.x, acc[1] + b4.y);
        u.y = pk2(acc[2] + b4.z, acc[3] + b4.w);
        *(uint2*)(dst + token * 80 + ft * 32 + 8 * quad) = u;
      }
    }
  }
  // ---- V: normal orientation (A = X, B = Wv rows) -> V^T[dim][key] ----
  #pragma unroll
  for (int ntd = 0; ntd < 2; ++ntd) {
    int vrow = 256 + h * 32 + ntd * 16 + m15;
    bf16x8 wv[4];
    #pragma unroll
    for (int kt = 0; kt < 4; ++kt)
      wv[kt] = *(const bf16x8*)(qkvw + vrow * 128 + kt * 32 + quad * 8);
    float vb = qkvb[vrow];
    #pragma unroll
    for (int t = 0; t < 2; ++t) {
      f32x4 acc = fz;
      #pragma unroll
      for (int kt = 0; kt < 4; ++kt)
        acc = __builtin_amdgcn_mfma_f32_16x16x32_bf16(xf[t][kt], wv[kt], acc, 0, 0, 0);
      int dim = ntd * 16 + m15;
      uint2 u;
      u.x = pk2(acc[0] + vb, acc[1] + vb);
      u.y = pk2(acc[2] + vb, acc[3] + vb);
      *(uint2*)(Hv + dim * 144 + ((half * 2 + t) * 16 + 4 * quad) * 2) = u;
    }
  }
  __syncthreads();                                             // S3

  // ---- S^T = K . Q^T (this wave: its 32 keys x all 64 queries) ----
  bf16x8 ka[2], qb[4];
  #pragma unroll
  for (int mk = 0; mk < 2; ++mk)
    ka[mk] = *(const bf16x8*)(Hk + ((half * 2 + mk) * 16 + m15) * 80 + quad * 16);
  #pragma unroll
  for (int nt = 0; nt < 4; ++nt)
    qb[nt] = *(const bf16x8*)(Hq + (nt * 16 + m15) * 80 + quad * 16);
  f32x4 sacc[2][4];
  #pragma unroll
  for (int mk = 0; mk < 2; ++mk)
    #pragma unroll
    for (int nt = 0; nt < 4; ++nt)
      sacc[mk][nt] = __builtin_amdgcn_mfma_f32_16x16x32_bf16(ka[mk], qb[nt], fz, 0, 0, 0);

  // ---- softmax (scores <= ~2: no max subtraction needed) ----
  #pragma unroll
  for (int nt = 0; nt < 4; ++nt) {
    int query = nt * 16 + m15;
    float ls = 0.f;
    #pragma unroll
    for (int mk = 0; mk < 2; ++mk) {
      int kb = (half * 2 + mk) * 16 + 4 * quad;
      float bm0 = 0.f, bm1 = 0.f, bm2 = 0.f, bm3 = 0.f;
      if (query < 49) {
        float4 bb = *(const float4*)(b2dp + (h * 49 + query) * 64 + kb);
        uint2 mm = *(const uint2*)(maskp + (wrem * 49 + query) * 64 + kb);
        bm0 = bb.x + bf2f(mm.x & 0xffffu);
        bm1 = bb.y + bf2f(mm.x >> 16);
        bm2 = bb.z + bf2f(mm.y & 0xffffu);
        bm3 = bb.w + bf2f(mm.y >> 16);
      }
      float s0 = (query < 49) ? fmaf(sacc[mk][nt][0], 0.17677669529663687f, bm0) : 0.f;
      float s1 = (query < 49) ? fmaf(sacc[mk][nt][1], 0.17677669529663687f, bm1) : 0.f;
      float s2 = (query < 49) ? fmaf(sacc[mk][nt][2], 0.17677669529663687f, bm2) : 0.f;
      float s3 = (query < 49) ? fmaf(sacc[mk][nt][3], 0.17677669529663687f, bm3) : 0.f;
      float e0 = __expf(s0), e1 = __expf(s1), e2 = __expf(s2), e3 = __expf(s3);
      sacc[mk][nt][0] = e0; sacc[mk][nt][1] = e1;
      sacc[mk][nt][2] = e2; sacc[mk][nt][3] = e3;
      ls += e0 + e1 + e2 + e3;
    }
    ls += __shfl_xor(ls, 16);
    ls += __shfl_xor(ls, 32);
    if (quad == 0) part[h * 128 + query * 2 + half] = ls;
  }
  __syncthreads();                                             // S4
  #pragma unroll
  for (int nt = 0; nt < 4; ++nt) {
    int query = nt * 16 + m15;
    float2 pq = *(const float2*)(part + h * 128 + query * 2);
    float rinv = 1.f / (pq.x + pq.y);
    #pragma unroll
    for (int mk = 0; mk < 2; ++mk) {
      uint2 u;
      u.x = pk2(sacc[mk][nt][0] * rinv, sacc[mk][nt][1] * rinv);
      u.y = pk2(sacc[mk][nt][2] * rinv, sacc[mk][nt][3] * rinv);
      *(uint2*)(Hq + query * 144 + ((half * 2 + mk) * 16 + 4 * quad) * 2) = u;  // P
    }
  }
  __syncthreads();                                             // S5

  // ---- O^T = V^T . P (this wave: all 32 dims x its 32 queries) ----
  bf16x8 va[2][2], pfr[2][2];
  #pragma unroll
  for (int mtd = 0; mtd < 2; ++mtd)
    #pragma unroll
    for (int kt = 0; kt < 2; ++kt)
      va[mtd][kt] = *(const bf16x8*)(Hv + (mtd * 16 + m15) * 144 + kt * 64 + quad * 16);
  #pragma unroll
  for (int t = 0; t < 2; ++t)
    #pragma unroll
    for (int kt = 0; kt < 2; ++kt)
      pfr[t][kt] = *(const bf16x8*)(Hq + ((half * 2 + t) * 16 + m15) * 144 + kt * 64 + quad * 16);
  #pragma unroll
  for (int mtd = 0; mtd < 2; ++mtd)
    #pragma unroll
    for (int t = 0; t < 2; ++t) {
      f32x4 acc = fz;
      #pragma unroll
      for (int kt = 0; kt < 2; ++kt)
        acc = __builtin_amdgcn_mfma_f32_16x16x32_bf16(va[mtd][kt], pfr[t][kt], acc, 0, 0, 0);
      int query = (half * 2 + t) * 16 + m15;
      uint2 u; u.x = pk2(acc[0], acc[1]); u.y = pk2(acc[2], acc[3]);
      *(uint2*)(Hq + query * 144 + (mtd * 16 + 4 * quad) * 2) = u;   // O over P (own rows)
    }
  __syncthreads();                                             // S6

  // ---- proj: Y^T = Wp . O^T; wave wid owns couts [wid*16, wid*16+16) ----
  const int mtc = wid;
  bf16x8 awf[4];
  #pragma unroll
  for (int kt = 0; kt < 4; ++kt)
    awf[kt] = *(const bf16x8*)(projw + (mtc * 16 + m15) * 128 + kt * 32 + quad * 8);
  float4 pb4 = *(const float4*)(projb + mtc * 16 + 4 * quad);
  const size_t obase = (size_t)b * 1605632;
  #pragma unroll
  for (int nt = 0; nt < 4; ++nt) {
    f32x4 acc = fz;
    #pragma unroll
    for (int kt = 0; kt < 4; ++kt) {
      bf16x8 ob = *(const bf16x8*)(smem + kt * 14848 + (nt * 16 + m15) * 144 + quad * 16);
      acc = __builtin_amdgcn_mfma_f32_16x16x32_bf16(awf[kt], ob, acc, 0, 0, 0);
    }
    int token = nt * 16 + m15;
    if (token < 49) {
      int ii = token / 7, jj = token - ii * 7;
      int gh = wh * 7 + ii + 3; if (gh >= 112) gh -= 112;
      int gw = ww * 7 + jj + 3; if (gw >= 112) gw -= 112;
      uint2 u;
      u.x = pk2(acc[0] + pb4.x, acc[1] + pb4.y);
      u.y = pk2(acc[2] + pb4.z, acc[3] + pb4.w);
      *(uint2*)(yw + obase + (size_t)(gh * 112 + gw) * 128 + mtc * 16 + 4 * quad) = u;
    }
  }
}

// ---------------------------------------------------------------------------
// Kernel 3: yws (B,H,W,C) bf16 + shortcut x (B,C,H,W) fp32 -> out fp32 NCHW.
// LDS staged [w][c] (stride 136): b128 writes balanced, scalar reads 2-way.
// ---------------------------------------------------------------------------
__global__ __launch_bounds__(256) void k_out(const unsigned short* __restrict__ yws,
                                             const float* __restrict__ x,
                                             float* __restrict__ out) {
  __shared__ unsigned short T[112 * 136];
  int tid = threadIdx.x;
  int bid = blockIdx.x;
  int b = bid / 112;
  int hh = bid - b * 112;
  const unsigned short* src = yws + (size_t)(b * 112 + hh) * 14336;
  #pragma unroll
  for (int it = 0; it < 7; ++it) {
    int cc = tid + it * 256;                 // 1792 chunks of 8 channels
    int w = cc >> 4, c8 = (cc & 15) * 8;
    ushort8 v = *(const ushort8*)(src + w * 128 + c8);
    *(ushort8*)(T + w * 136 + c8) = v;
  }
  __syncthreads();
  int c = tid >> 1, half = tid & 1;
  size_t rowoff = ((size_t)(b * 128 + c) * 112 + hh) * 112;
  const float* xr = x + rowoff;
  float* outr = out + rowoff;
  #pragma unroll
  for (int s2 = 0; s2 < 7; ++s2) {
    int w = half * 56 + s2 * 8;
    float4 xa = *(const float4*)(xr + w);
    float4 xb = *(const float4*)(xr + w + 4);
    float4 oa, ob;
    oa.x = bf2f(T[(w + 0) * 136 + c]) + xa.x;
    oa.y = bf2f(T[(w + 1) * 136 + c]) + xa.y;
    oa.z = bf2f(T[(w + 2) * 136 + c]) + xa.z;
    oa.w = bf2f(T[(w + 3) * 136 + c]) + xa.w;
    ob.x = bf2f(T[(w + 4) * 136 + c]) + xb.x;
    ob.y = bf2f(T[(w + 5) * 136 + c]) + xb.y;
    ob.z = bf2f(T[(w + 6) * 136 + c]) + xb.z;
    ob.w = bf2f(T[(w + 7) * 136 + c]) + xb.w;
    *(float4*)(outr + w) = oa;
    *(float4*)(outr + w + 4) = ob;
  }
}

// ---------------------------------------------------------------------------
extern "C" void kernel_launch(void* const* d_in, const int* in_sizes, int n_in,
                              void* d_out, int out_size, void* d_ws, size_t ws_size,
                              hipStream_t stream) {
  const float* x     = (const float*)d_in[0];
  const float* nw    = (const float*)d_in[1];
  const float* nb    = (const float*)d_in[2];
  const float* qkvw  = (const float*)d_in[3];
  const float* qkvb  = (const float*)d_in[4];
  const float* projw = (const float*)d_in[5];
  const float* projb = (const float*)d_in[6];
  const float* bt    = (const float*)d_in[7];
  const int*   ri    = (const int*)d_in[8];
  const float* am    = (const float*)d_in[9];

  unsigned short* xw    = (unsigned short*)d_ws;                        // 102,760,448 B
  unsigned short* yws   = (unsigned short*)((char*)d_ws + 102760448);   // 102,760,448 B
  float*          b2dp  = (float*)((char*)d_ws + 205520896);            //      50,176 B
  unsigned short* maskp = (unsigned short*)((char*)d_ws + 205571072);   //   1,605,632 B
  unsigned short* qwbf  = (unsigned short*)((char*)d_ws + 207176704);   //      98,304 B
  unsigned short* pwbf  = (unsigned short*)((char*)d_ws + 207275008);   //      32,768 B
  float* out = (float*)d_out;

  k_prep <<<64,   256, 0, stream>>>(qkvw, projw, qwbf, pwbf);
  k_biasp<<<49,   256, 0, stream>>>(bt, ri, b2dp);
  k_maskp<<<3136, 256, 0, stream>>>(am, maskp);
  k_ln   <<<1568, 256, 0, stream>>>(x, nw, nb, xw);
  k_attn <<<8192, 512, 0, stream>>>(xw, qwbf, qkvb, pwbf, projb, b2dp, maskp, yws);
  k_out  <<<3584, 256, 0, stream>>>(yws, x, out);
}